// Round 1
// baseline (217.458 us; speedup 1.0000x reference)
//
#include <hip/hip_runtime.h>
#include <hip/hip_bf16.h>

// Problem constants
#define B_    8
#define CIN   128
#define H_    64
#define W_    64
#define COUT  128
#define K_    16
#define HO    61
#define WO    61
#define HW_   (HO * WO)          // 3721
#define KKTOT (CIN * K_)         // 2048
#define BSH   256                // kk per Bs half (16 channels)
#define TROWS 12                 // tile rows (±4 sigma margins after ki centering)
#define TILW  40                 // tile row stride (words): bank = (8*row+col)%32
#define TILCH 4                  // channels per tile group
#define TILSZ (TILCH * TROWS * TILW) // 1920 floats = 7.5 KB per buffer

typedef short bf16x8 __attribute__((ext_vector_type(8)));
typedef float f32x4  __attribute__((ext_vector_type(4)));
typedef float f32x2u __attribute__((ext_vector_type(2), aligned(4)));
typedef float f32x4u __attribute__((ext_vector_type(4), aligned(4)));

// Pre-flip weight (transposed-conv: k' = 15-k), bf16.  A[o][c*16+k] = w[o][c][15-k]
__global__ __launch_bounds__(256) void prep_weight(const float* __restrict__ w,
                                                   __hip_bfloat16* __restrict__ A) {
    int idx = blockIdx.x * 256 + threadIdx.x;
    int o   = idx >> 11;
    int rem = idx & 2047;
    int c   = rem >> 4;
    int k   = rem & 15;
    A[idx]  = __float2bfloat16(w[(o << 11) + (c << 4) + (15 - k)]);
}

// Block = 16 pixels of one (b,ho) row segment x 128 couts. 256 thr = (pix, tap).
// Pipelined: tile double-buffered (2x7.5 KB), Bs double-buffered halves (2x8 KB)
// -> ONE barrier per 4-channel group (33/block vs 68), MFMA chunks of the
// previous Bs half interleaved into every group (A-loads hoisted to hide L2
// latency under the gather).  LDS = 31744 B -> 5 blocks/CU (20 waves).
__global__ __launch_bounds__(256, 5) void deform_main(
        const float* __restrict__ inp, const float* __restrict__ off,
        const float* __restrict__ msk, const __hip_bfloat16* __restrict__ A,
        const float* __restrict__ bias, float* __restrict__ out) {

    __shared__ __align__(16) __hip_bfloat16 Bs[2][16 * BSH];  // 2 x 8 KB
    __shared__ __align__(16) float tile[2][TILSZ];            // 2 x 7.5 KB

    const int t   = threadIdx.x;
    const int pix = t & 15;
    const int k   = t >> 4;            // tap 0..15

    // ---- block decode: bid&7 = batch (XCD/L2 pinning) ----
    const int bid = blockIdx.x;
    const int b   = bid & 7;
    const int g_  = bid >> 3;
    const int ho  = g_ >> 2;
    const int wt  = (g_ & 3) << 4;
    const int wo  = wt + pix;
    const bool pvalid = (wo < WO);
    const int wo_c = pvalid ? wo : (WO - 1);
    const int r    = ho * WO + wo_c;

    // ---- window: 12 rows x 32 cols; ki-centered margins (+-4 rows worst-tap) ----
    const int ry_lo = min(max(ho - 4, 0), H_ - TROWS);
    const int cx_lo = min(max(wt - 6, 0), W_ - 32) & ~3;

    // ---- per-(pixel,tap) sampling params ----
    const int ki = k >> 2, kj = k & 3;
    const size_t offb = (size_t)b * (2 * K_ * HW_);
    float dy = off[offb + (size_t)(2 * k)     * HW_ + r];
    float dx = off[offb + (size_t)(2 * k + 1) * HW_ + r];
    float mm = msk[(size_t)b * (K_ * HW_) + (size_t)k * HW_ + r];
    if (!pvalid) mm = 0.0f;

    float y   = dy + (float)(ki + ho);
    float x   = dx + (float)(kj + wo_c);
    float y0f = floorf(y), x0f = floorf(x);
    float wy  = y - y0f,   wx  = x - x0f;
    int y0 = (int)y0f, x0 = (int)x0f;
    int y1 = y0 + 1,   x1 = x0 + 1;

    float wy0v = (1.0f - wy) * ((y0 >= 0 && y0 < H_) ? mm : 0.0f);
    float wy1v = wy          * ((y1 >= 0 && y1 < H_) ? mm : 0.0f);
    int cy0 = min(max(y0, 0), H_ - 1), cy1 = min(max(y1, 0), H_ - 1);

    float wx0v = (1.0f - wx) * ((x0 >= 0 && x0 < W_) ? 1.0f : 0.0f);
    float wx1v = wx          * ((x1 >= 0 && x1 < W_) ? 1.0f : 0.0f);
    int xb = min(max(x0, 0), W_ - 2);
    int tsh = x0 - xb;                 // -1,0,1 (else both x-weights are 0)
    float a0 = (tsh == 0) ? wx0v : ((tsh == -1) ? wx1v : 0.0f);
    float a1 = (tsh == 0) ? wx1v : ((tsh ==  1) ? wx0v : 0.0f);

    const float b00 = wy0v * a0, b01 = wy0v * a1;
    const float b10 = wy1v * a0, b11 = wy1v * a1;
    const int ad0 = cy0 * W_ + xb;     // exact global fallback addrs
    const int ad1 = cy1 * W_ + xb;

    // tile coords + in-window test (fallback handles the sigma tail exactly)
    int t0 = cy0 - ry_lo, t1 = cy1 - ry_lo, u = xb - cx_lo;
    const bool intile = (t0 >= 0) & (t0 < TROWS) & (t1 >= 0) & (t1 < TROWS) &
                        (u >= 0) & (u <= 30);
    const float l00 = intile ? b00 : 0.0f, l01 = intile ? b01 : 0.0f;
    const float l10 = intile ? b10 : 0.0f, l11 = intile ? b11 : 0.0f;
    const int tc0 = min(max(t0, 0), TROWS - 1) * TILW + min(max(u, 0), 30);
    const int tc1 = min(max(t1, 0), TROWS - 1) * TILW + min(max(u, 0), 30);

    const float* pin = inp + (size_t)b * (CIN * H_ * W_);

    // ---- staging chunk geometry: 384 chunks = 4ch x 12row x 8colgrp, 16B each
    //      thread t does chunk t; threads t<128 also do chunk 256+t ----
    int soff[2];   // global dword offset within a 4-channel group
    int lofs[2];   // LDS dword offset within one tile buffer
    #pragma unroll
    for (int j = 0; j < 2; ++j) {
        int C   = j * 256 + t;
        int chl = C / 96;              // 0..3 (j=1,t<128 -> 2..3)
        int rem = C - chl * 96;
        int row = rem >> 3;            // 0..11
        int c4  = rem & 7;             // 0..7 (4-dword col group)
        soff[j] = (chl << 12) + (ry_lo + row) * W_ + cx_lo + (c4 << 2);
        lofs[j] = chl * (TROWS * TILW) + row * TILW + (c4 << 2);
    }
    const bool half2 = (t < 128);

    // MFMA identity
    const int lane = t & 63;
    const int wv   = t >> 6;
    const int quad = lane >> 4;
    const int mrow = lane & 15;        // == pix
    const int q8   = quad << 3;
    const __hip_bfloat16* Arow0 = A + ((size_t)(wv * 32 + mrow) << 11);
    const __hip_bfloat16* Arow1 = Arow0 + (16 << 11);
    const int brot = mrow << 3;

    f32x4 acc0 = {0.f, 0.f, 0.f, 0.f};
    f32x4 acc1 = {0.f, 0.f, 0.f, 0.f};

    // ---- preload group 0 (channels 0..3) into tile[0] ----
    f32x4u pf0 = *(const f32x4u*)(const void*)(pin + soff[0]);
    f32x4u pf1 = {0.f, 0.f, 0.f, 0.f};
    if (half2) pf1 = *(const f32x4u*)(const void*)(pin + soff[1]);
    *(f32x4u*)(void*)(&tile[0][lofs[0]]) = pf0;
    if (half2) *(f32x4u*)(void*)(&tile[0][lofs[1]]) = pf1;
    __syncthreads();

    #pragma unroll 1
    for (int h = 0; h < 8; ++h) {      // Bs half being STAGED
        #pragma unroll 1
        for (int gi = 0; gi < 4; ++gi) {
            const int g    = (h << 2) + gi;     // 4-channel group
            const bool dopf = (g != 31);
            const int gn   = (g + 1) & 31;

            // (1) issue next-group prefetch (global, consumed at tile write)
            if (dopf) {
                pf0 = *(const f32x4u*)(const void*)(pin + (gn << 14) + soff[0]);
                if (half2)
                    pf1 = *(const f32x4u*)(const void*)(pin + (gn << 14) + soff[1]);
            }

            // (2) hoist MFMA operands for previous half: A from global (L2
            //     latency hides under the gather), B from the settled Bs half
            bf16x8 av0a = {}, av1a = {}, av0b = {}, av1b = {}, bba = {}, bbb = {};
            const int kkA = (gi << 6) + q8;     // it = gi*2   -> kk = it*32+q8
            const int kkB = kkA + 32;           // it = gi*2+1
            if (h > 0) {
                const int hp = h - 1;
                const __hip_bfloat16* Aq0 = Arow0 + (hp << 8);
                const __hip_bfloat16* Aq1 = Arow1 + (hp << 8);
                const __hip_bfloat16* bsb = &Bs[hp & 1][mrow << 8];
                av0a = *(const bf16x8*)(const void*)(Aq0 + kkA);
                av1a = *(const bf16x8*)(const void*)(Aq1 + kkA);
                av0b = *(const bf16x8*)(const void*)(Aq0 + kkB);
                av1b = *(const bf16x8*)(const void*)(Aq1 + kkB);
                bba  = *(const bf16x8*)(const void*)(bsb + ((kkA + brot) & (BSH - 1)));
                bbb  = *(const bf16x8*)(const void*)(bsb + ((kkB + brot) & (BSH - 1)));
            }

            // (3) gather 4 channels from tile[g&1] -> Bs[h&1]
            const int cbase = g << 2;
            #pragma unroll
            for (int c4 = 0; c4 < 4; ++c4) {
                const float* tb = &tile[g & 1][c4 * (TROWS * TILW)];
                f32x2u f0 = *(const f32x2u*)(const void*)(tb + tc0);
                f32x2u f1 = *(const f32x2u*)(const void*)(tb + tc1);
                float s = l00 * f0[0] + l01 * f0[1] + l10 * f1[0] + l11 * f1[1];
                if (!intile) {         // exec-skipped ~always; exact tail
                    const float* p = pin + ((size_t)(cbase + c4) << 12);
                    f32x2u h0 = *(const f32x2u*)(const void*)(p + ad0);
                    f32x2u h1 = *(const f32x2u*)(const void*)(p + ad1);
                    s += b00 * h0[0] + b01 * h0[1] + b10 * h1[0] + b11 * h1[1];
                }
                int kkl = (((cbase + c4) & 15) << 4) + k;
                Bs[h & 1][(pix << 8) + ((kkl + (pix << 3)) & (BSH - 1))] =
                    __float2bfloat16(s);
            }

            // (4) MFMA chunk of previous half (operands already in regs)
            if (h > 0) {
                __builtin_amdgcn_s_setprio(1);
                acc0 = __builtin_amdgcn_mfma_f32_16x16x32_bf16(av0a, bba, acc0, 0, 0, 0);
                acc1 = __builtin_amdgcn_mfma_f32_16x16x32_bf16(av1a, bba, acc1, 0, 0, 0);
                acc0 = __builtin_amdgcn_mfma_f32_16x16x32_bf16(av0b, bbb, acc0, 0, 0, 0);
                acc1 = __builtin_amdgcn_mfma_f32_16x16x32_bf16(av1b, bbb, acc1, 0, 0, 0);
                __builtin_amdgcn_s_setprio(0);
            }

            // (5) write prefetched group into the other tile buffer
            if (dopf) {
                float* tw = &tile[(g + 1) & 1][0];
                *(f32x4u*)(void*)(tw + lofs[0]) = pf0;
                if (half2) *(f32x4u*)(void*)(tw + lofs[1]) = pf1;
            }
            __syncthreads();           // single barrier per group
        }
    }

    // ---- epilogue MFMA: last half (hp=7, Bs[1]) ----
    {
        const __hip_bfloat16* Aq0 = Arow0 + (7 << 8);
        const __hip_bfloat16* Aq1 = Arow1 + (7 << 8);
        const __hip_bfloat16* bsb = &Bs[1][mrow << 8];
        #pragma unroll 4
        for (int it = 0; it < 8; ++it) {
            const int kk0 = (it << 5) + q8;
            bf16x8 av0 = *(const bf16x8*)(const void*)(Aq0 + kk0);
            bf16x8 av1 = *(const bf16x8*)(const void*)(Aq1 + kk0);
            bf16x8 bb  = *(const bf16x8*)(const void*)(bsb + ((kk0 + brot) & (BSH - 1)));
            acc0 = __builtin_amdgcn_mfma_f32_16x16x32_bf16(av0, bb, acc0, 0, 0, 0);
            acc1 = __builtin_amdgcn_mfma_f32_16x16x32_bf16(av1, bb, acc1, 0, 0, 0);
        }
    }

    // ---- epilogue: C/D col=lane&15 (pixel), row=quad*4+j (cout) ----
    if (pvalid) {
        size_t outb = (size_t)b * (COUT * HW_) + r;
        #pragma unroll
        for (int j = 0; j < 4; ++j) {
            int o = wv * 32 + quad * 4 + j;
            out[outb + (size_t)o        * HW_] = acc0[j] + bias[o];
            out[outb + (size_t)(o + 16) * HW_] = acc1[j] + bias[o + 16];
        }
    }
}

extern "C" void kernel_launch(void* const* d_in, const int* in_sizes, int n_in,
                              void* d_out, int out_size, void* d_ws, size_t ws_size,
                              hipStream_t stream) {
    const float* inp  = (const float*)d_in[0];
    const float* off  = (const float*)d_in[1];
    const float* msk  = (const float*)d_in[2];
    const float* wgt  = (const float*)d_in[3];
    const float* bias = (const float*)d_in[4];
    float* out = (float*)d_out;

    __hip_bfloat16* A = (__hip_bfloat16*)d_ws;   // 512 KB

    prep_weight<<<(COUT * KKTOT) / 256, 256, 0, stream>>>(wgt, A);

    int nblk = B_ * HO * 4;            // 1952 (bid&7 = batch)
    deform_main<<<nblk, 256, 0, stream>>>(inp, off, msk, A, bias, out);
}